// Round 11
// baseline (231.040 us; speedup 1.0000x reference)
//
#include <hip/hip_runtime.h>
#include <hip/hip_bf16.h>
#include <stdint.h>

#define NT 16320      // 64 * 255
#define NTPAD 16384
#define KDIM 128      // padded from 100
#define NCOLS 4096    // K*K
#define NSEQ 64
#define TSTEPS 255
#define VOCAB 32000
#define EDIM 100
#define CHUNKS 32     // chunks of 8 steps (last = 7); 31*8+7 = 255
#define CLEN 8

typedef __attribute__((ext_vector_type(8))) short s8v;
typedef __attribute__((ext_vector_type(4))) float f4v;

__device__ __forceinline__ float bflo(uint32_t u) { return __uint_as_float(u << 16); }
__device__ __forceinline__ float bfhi(uint32_t u) { return __uint_as_float(u & 0xffff0000u); }

// async global->LDS, 16B per lane; lane i writes lds_base + i*16 (wave-uniform base)
__device__ __forceinline__ void load_lds16(const void* g, void* l) {
    __builtin_amdgcn_global_load_lds(
        (const __attribute__((address_space(1))) void*)(uintptr_t)g,
        (__attribute__((address_space(3))) void*)(uintptr_t)l,
        16, 0, 0);
}

// ---------------- fused: prep A+B (blocks 0..1279) + dkern (blocks 1280..1535)
__global__ __launch_bounds__(256) void prep_dk(const int* __restrict__ x,
                                               const float* __restrict__ emb,
                                               const float* __restrict__ Wt,
                                               const float* __restrict__ ec,
                                               const float* __restrict__ vw,
                                               __hip_bfloat16* __restrict__ A,
                                               __hip_bfloat16* __restrict__ B,
                                               float* __restrict__ partials) {
    int bid = blockIdx.x;
    int tid = threadIdx.x;
    if (bid < 1280) {
        // ---- prep: 16 rows per block, 16 threads per row (8 cols each) ----
        int rloc = tid >> 4, q = tid & 15;
        int b = bid * 16 + rloc;
        int c0 = q * 8;
        float vals[8] = {0.f, 0.f, 0.f, 0.f, 0.f, 0.f, 0.f, 0.f};
        __hip_bfloat16* dst;
        if (b < NTPAD) {
            if (b < NT) {
                int n = b / TSTEPS;
                int t = b - n * TSTEPS;
                int tok = x[n * 256 + t];
                const float* er = emb + (size_t)tok * EDIM;
#pragma unroll
                for (int i = 0; i < 8; ++i) { int e = c0 + i; if (e < EDIM) vals[i] = er[e]; }
            }
            dst = A + (size_t)b * KDIM + c0;
        } else {
            int cc = b - NTPAD;
            const float* wr = Wt + (size_t)cc * EDIM;
#pragma unroll
            for (int i = 0; i < 8; ++i) { int e = c0 + i; if (e < EDIM) vals[i] = wr[e]; }
            dst = B + (size_t)cc * KDIM + c0;
        }
        union { __hip_bfloat16 h[8]; uint4 u; } pk;
#pragma unroll
        for (int i = 0; i < 8; ++i) pk.h[i] = __float2bfloat16(vals[i]);
        *(uint4*)dst = pk.u;
    } else {
        // ---- dkern: emission-denominator partial lse, register-cached ec ----
        int db = bid - 1280;
        int wave = tid >> 6, lane = tid & 63;
        float er[64];
        {
            const float4* ecv = (const float4*)(ec + (size_t)lane * 64);
#pragma unroll
            for (int i = 0; i < 16; ++i) {
                float4 v = ecv[i];
                er[4 * i] = v.x; er[4 * i + 1] = v.y; er[4 * i + 2] = v.z; er[4 * i + 3] = v.w;
            }
        }
        int v0 = db * 125;
        float m = -1e30f, s = 0.f;
        for (int v = v0 + wave; v < v0 + 125; v += 4) {
            int vu = __builtin_amdgcn_readfirstlane(v);
            const float* row = vw + (size_t)vu * 64;
            float acc = 0.f;
#pragma unroll
            for (int e = 0; e < 64; ++e) acc += er[e] * row[e];
            float nm = fmaxf(m, acc);
            s = s * __expf(m - nm) + __expf(acc - nm);
            m = nm;
        }
        __shared__ float pm[4][64], ps[4][64];
        pm[wave][lane] = m; ps[wave][lane] = s;
        __syncthreads();
        if (tid < 64) {
            float M = pm[0][tid], Ssum = ps[0][tid];
#pragma unroll
            for (int w = 1; w < 4; ++w) {
                float m2 = pm[w][tid], s2 = ps[w][tid];
                float nm = fmaxf(M, m2);
                Ssum = Ssum * __expf(M - nm) + s2 * __expf(m2 - nm);
                M = nm;
            }
            partials[(db * 64 + tid) * 2]     = M;
            partials[(db * 64 + tid) * 2 + 1] = Ssum;
        }
    }
}

__global__ __launch_bounds__(256) void dreduce(const float* __restrict__ partials,
                                               float* __restrict__ d) {
    __shared__ float pm[4][64], ps[4][64];
    int k = threadIdx.x & 63, part = threadIdx.x >> 6;
    float M = -1e30f, S = 0.f;
    for (int b = part; b < 256; b += 4) {
        float m2 = partials[(b * 64 + k) * 2];
        float s2 = partials[(b * 64 + k) * 2 + 1];
        float nm = fmaxf(M, m2);
        S = S * __expf(M - nm) + s2 * __expf(m2 - nm);
        M = nm;
    }
    pm[part][k] = M; ps[part][k] = S;
    __syncthreads();
    if (threadIdx.x < 64) {
        float Mm = pm[0][k], Ss = ps[0][k];
#pragma unroll
        for (int w = 1; w < 4; ++w) {
            float m2 = pm[w][k], s2 = ps[w][k];
            float nm = fmaxf(Mm, m2);
            Ss = Ss * __expf(Mm - nm) + s2 * __expf(m2 - nm);
            Mm = nm;
        }
        d[k] = Mm + __logf(Ss);
    }
}

// ---------------- emissions: register-cached ec, 4 tokens/wave ----------------
// pos(j) = ((j>>2)&3)*16 + ((j>>4)&3)*4 + (j&3)
__global__ __launch_bounds__(256) void emit_kern(const int* __restrict__ x,
                                                 const float* __restrict__ ec,
                                                 const float* __restrict__ vw,
                                                 const float* __restrict__ d,
                                                 __hip_bfloat16* __restrict__ emB) {
    int tid = threadIdx.x;
    int wave = tid >> 6, lane = tid & 63;
    float er[64];
    {
        const float4* ecv = (const float4*)(ec + (size_t)lane * 64);
#pragma unroll
        for (int i = 0; i < 16; ++i) {
            float4 v = ecv[i];
            er[4 * i] = v.x; er[4 * i + 1] = v.y; er[4 * i + 2] = v.z; er[4 * i + 3] = v.w;
        }
    }
    float dj = d[lane];
    int j = lane;
    int pos = ((j >> 2) & 3) * 16 + ((j >> 4) & 3) * 4 + (j & 3);
    int nt0 = blockIdx.x * 16 + wave * 4;     // grid 1020 -> 16320 exactly
#pragma unroll
    for (int s = 0; s < 4; ++s) {
        int nt = nt0 + s;
        int n = nt / TSTEPS;
        int t = nt - n * TSTEPS;
        int tok = x[n * 256 + t + 1];
        tok = __builtin_amdgcn_readfirstlane(tok);
        const float* row = vw + (size_t)tok * 64;
        float acc = 0.f;
#pragma unroll
        for (int e = 0; e < 64; ++e) acc += er[e] * row[e];
        emB[(size_t)nt * 64 + pos] = __float2bfloat16(__expf(acc - dj));
    }
}

// ---------------- GEMM (transposed) + softmax*em -> bf16 E --------------------
__global__ __launch_bounds__(256) void gemm_kern(const __hip_bfloat16* __restrict__ A,
                                                 const __hip_bfloat16* __restrict__ B,
                                                 const __hip_bfloat16* __restrict__ emB,
                                                 __hip_bfloat16* __restrict__ Eg) {
    int mblk = blockIdx.x;   // 0..127 (128 m rows)
    int nblk = blockIdx.y;   // 0..31  (128 c cols)
    int tid = threadIdx.x, wave = tid >> 6, lane = tid & 63;

    __shared__ __align__(16) char smem[65536];
    char* sA = smem;            // 128 m-rows * 256 B
    char* sB = smem + 32768;    // 128 c-rows * 256 B

    // ---- stage ----
    {
        int r0 = wave * 32;
        int l16 = lane & 15;
        int rsub = lane >> 4;
#pragma unroll
        for (int g = 0; g < 8; ++g) {
            int r = r0 + g * 4 + rsub;
            int chunk = l16 ^ (r & 7);
            const char* gp = (const char*)(A + (size_t)(mblk * 128 + r) * KDIM) + chunk * 16;
            load_lds16(gp, sA + (r0 + g * 4) * 256);
        }
#pragma unroll
        for (int g = 0; g < 8; ++g) {
            int c = r0 + g * 4 + rsub;
            int chunk = l16 ^ (c & 7);
            const char* gp = (const char*)(B + (size_t)(nblk * 128 + c) * KDIM) + chunk * 16;
            load_lds16(gp, sB + (r0 + g * 4) * 256);
        }
    }
    __syncthreads();

    // ---- compute: A-operand = W rows (c), B-operand = xe rows (m) ----
    int wc = (wave >> 1) * 64, wm = (wave & 1) * 64;
    int l15 = lane & 15, g4 = lane >> 4;
    f4v acc[4][4] = {};   // [jt(c-tile)][mt(m-tile)]
#pragma unroll
    for (int k32 = 0; k32 < 4; ++k32) {
        s8v af[4], bf[4];
#pragma unroll
        for (int jt = 0; jt < 4; ++jt) {
            int r = wc + jt * 16 + l15;
            int chunk = (k32 * 4 + g4) ^ (r & 7);
            af[jt] = *(const s8v*)(sB + r * 256 + chunk * 16);
        }
#pragma unroll
        for (int mt = 0; mt < 4; ++mt) {
            int r = wm + mt * 16 + l15;
            int chunk = (k32 * 4 + g4) ^ (r & 7);
            bf[mt] = *(const s8v*)(sA + r * 256 + chunk * 16);
        }
#pragma unroll
        for (int jt = 0; jt < 4; ++jt)
#pragma unroll
            for (int mt = 0; mt < 4; ++mt)
                acc[jt][mt] = __builtin_amdgcn_mfma_f32_16x16x32_bf16(af[jt], bf[mt], acc[jt][mt], 0, 0, 0);
    }
    __syncthreads();   // staging dead; reuse for sW

    // ---- epilogue: per col m: softmax over 64 j, * em, bf16 pack -> sW ----
    char* sW = smem;   // 128 m-rows * 272 B (256 data + 16 pad)
    const char* emb8 = (const char*)emB;
#pragma unroll
    for (int mt = 0; mt < 4; ++mt) {
        int mrow = wm + mt * 16 + l15;
        int mglob = mblk * 128 + mrow;
        float v[16];
#pragma unroll
        for (int jt = 0; jt < 4; ++jt)
#pragma unroll
            for (int rr = 0; rr < 4; ++rr) v[jt * 4 + rr] = acc[jt][mt][rr];
        float mx = v[0];
#pragma unroll
        for (int k = 1; k < 16; ++k) mx = fmaxf(mx, v[k]);
        mx = fmaxf(mx, __shfl_xor(mx, 16, 64));
        mx = fmaxf(mx, __shfl_xor(mx, 32, 64));
        float ex[16], sg = 0.f;
#pragma unroll
        for (int k = 0; k < 16; ++k) { ex[k] = __expf(v[k] - mx); sg += ex[k]; }
        sg += __shfl_xor(sg, 16, 64);
        sg += __shfl_xor(sg, 32, 64);
        float inv = 1.0f / sg;
        uint4 e0 = *(const uint4*)(emb8 + (size_t)mglob * 128 + g4 * 32);
        uint4 e1 = *(const uint4*)(emb8 + (size_t)mglob * 128 + g4 * 32 + 16);
        float em[16];
        {
            const uint32_t* w0 = (const uint32_t*)&e0;
            const uint32_t* w1 = (const uint32_t*)&e1;
#pragma unroll
            for (int i = 0; i < 4; ++i) {
                em[2 * i] = bflo(w0[i]);     em[2 * i + 1] = bfhi(w0[i]);
                em[8 + 2 * i] = bflo(w1[i]); em[8 + 2 * i + 1] = bfhi(w1[i]);
            }
        }
#pragma unroll
        for (int jt = 0; jt < 4; ++jt) {
            union { __hip_bfloat16 h[4]; uint2 u; } pk;
#pragma unroll
            for (int rr = 0; rr < 4; ++rr)
                pk.h[rr] = __float2bfloat16(ex[jt * 4 + rr] * inv * em[jt * 4 + rr]);
            *(uint2*)(sW + mrow * 272 + (wc + jt * 16 + g4 * 4) * 2) = pk.u;
        }
    }
    __syncthreads();

    // ---- coalesced store: per wave-instruction 8 rows x 128 B contiguous ----
    {
        int rloc = tid >> 3;          // 0..31
        int q = tid & 7;              // 16 B chunk within 128 B half
#pragma unroll
        for (int rp = 0; rp < 4; ++rp) {
            int row = rp * 32 + rloc;
            char* dst = (char*)Eg + (size_t)(mblk * 128 + row) * 8192 + nblk * 256;
            const char* src = sW + row * 272;
            *(uint4*)(dst + q * 16)       = *(const uint4*)(src + q * 16);
            *(uint4*)(dst + 128 + q * 16) = *(const uint4*)(src + 128 + q * 16);
        }
    }
}

// ---------------- chunk: one wave per chunk (8 steps), barrier-free, bf16 -----
__global__ __launch_bounds__(64) void chunk_kern(const __hip_bfloat16* __restrict__ Eg,
                                                 __hip_bfloat16* __restrict__ Gout,
                                                 float* __restrict__ Rout) {
    int lane = threadIdx.x;
    int l15 = lane & 15, g4 = lane >> 4;
    int id = blockIdx.x;               // 0..2047
    int n = id >> 5;
    int c = id & 31;
    int base_m = n * TSTEPS + c * CLEN;
    int len = (c == 31) ? 7 : 8;

    __shared__ __align__(16) char sGT[64 * 144];   // 9216 B

    // init identity: lane owns row (= column) `lane`
    {
        uint4 z = {0, 0, 0, 0};
#pragma unroll
        for (int i = 0; i < 8; ++i) *(uint4*)(sGT + lane * 144 + i * 16) = z;
        *(uint16_t*)(sGT + lane * 144 + lane * 2) = 0x3F80;   // bf16 1.0
    }

    const char* Ebase = (const char*)Eg;
    uint4 pf[4][2];
    {
        const char* tp = Ebase + (size_t)(base_m + len - 1) * 8192;
#pragma unroll
        for (int at = 0; at < 4; ++at)
#pragma unroll
            for (int kk = 0; kk < 2; ++kk)
                pf[at][kk] = *(const uint4*)(tp + (at * 16 + l15) * 128 + kk * 64 + g4 * 16);
    }

    float rlog[4] = {0.f, 0.f, 0.f, 0.f};

    for (int tl = len - 1; tl >= 0; --tl) {
        uint4 af[4][2];
#pragma unroll
        for (int at = 0; at < 4; ++at) { af[at][0] = pf[at][0]; af[at][1] = pf[at][1]; }
        if (tl > 0) {
            const char* tp = Ebase + (size_t)(base_m + tl - 1) * 8192;
#pragma unroll
            for (int at = 0; at < 4; ++at)
#pragma unroll
                for (int kk = 0; kk < 2; ++kk)
                    pf[at][kk] = *(const uint4*)(tp + (at * 16 + l15) * 128 + kk * 64 + g4 * 16);
        }

        f4v acc[4][4] = {};   // [at(m-tile)][ct(n-tile)]
#pragma unroll
        for (int kk = 0; kk < 2; ++kk) {
#pragma unroll
            for (int ct = 0; ct < 4; ++ct) {
                s8v b = *(const s8v*)(sGT + (ct * 16 + l15) * 144 + kk * 64 + g4 * 16);
#pragma unroll
                for (int at = 0; at < 4; ++at)
                    acc[at][ct] = __builtin_amdgcn_mfma_f32_16x16x32_bf16(
                        *(const s8v*)&af[at][kk], b, acc[at][ct], 0, 0, 0);
            }
        }

        // colmax-normalize per ct (col = ct*16 + l15)
#pragma unroll
        for (int ct = 0; ct < 4; ++ct) {
            float mx = acc[0][ct][0];
#pragma unroll
            for (int at = 0; at < 4; ++at)
#pragma unroll
                for (int rr = 0; rr < 4; ++rr) mx = fmaxf(mx, acc[at][ct][rr]);
            mx = fmaxf(mx, __shfl_xor(mx, 16, 64));
            mx = fmaxf(mx, __shfl_xor(mx, 32, 64));
            mx = fmaxf(mx, 1e-38f);
            rlog[ct] += __logf(mx);
            float inv = 1.0f / mx;
            int col = ct * 16 + l15;
#pragma unroll
            for (int at = 0; at < 4; ++at) {
                union { __hip_bfloat16 h[4]; uint2 u; } pk;
#pragma unroll
                for (int rr = 0; rr < 4; ++rr)
                    pk.h[rr] = __float2bfloat16(acc[at][ct][rr] * inv);
                *(uint2*)(sGT + col * 144 + at * 32 + g4 * 8) = pk.u;
            }
        }
    }

    // ---- output: Gout[id*4096 + c*64 + a] = W[a][c]; lane -> col = lane ----
    {
        char* go = (char*)(Gout + (size_t)id * 4096 + lane * 64);
#pragma unroll
        for (int i = 0; i < 8; ++i)
            *(uint4*)(go + i * 16) = *(const uint4*)(sGT + lane * 144 + i * 16);
    }
    if (g4 == 0)
#pragma unroll
        for (int ct = 0; ct < 4; ++ct)
            Rout[(size_t)id * 64 + ct * 16 + l15] = rlog[ct];
}

// ---------------- combine: ONE WAVE per sequence, barrier-free ----------------
__global__ __launch_bounds__(64) void combine_kern(const __hip_bfloat16* __restrict__ G,
                                                   const float* __restrict__ R,
                                                   const float* __restrict__ sw,
                                                   const float* __restrict__ sb,
                                                   float* __restrict__ out) {
    int n = blockIdx.x;
    int lane = threadIdx.x;
    __shared__ __align__(16) float sV[64];

    float alpha;
    {
        float v = sw[lane] + sb[lane];
        float m = v;
#pragma unroll
        for (int off = 1; off < 64; off <<= 1) m = fmaxf(m, __shfl_xor(m, off, 64));
        float s = __expf(v - m);
#pragma unroll
        for (int off = 1; off < 64; off <<= 1) s += __shfl_xor(s, off, 64);
        alpha = v - (m + __logf(s));
    }

    const char* Gb = (const char*)(G + (size_t)n * CHUNKS * 4096) + lane * 128;
    const float* Rb = R + (size_t)n * CHUNKS * 64 + lane;

    uint4 pf[8];
#pragma unroll
    for (int i = 0; i < 8; ++i) pf[i] = *(const uint4*)(Gb + i * 16);
    float rpf = Rb[0];

    for (int c = 0; c < CHUNKS; ++c) {
        uint4 cur[8];
#pragma unroll
        for (int i = 0; i < 8; ++i) cur[i] = pf[i];
        float rc = rpf;
        if (c + 1 < CHUNKS) {
            const char* gn = Gb + (size_t)(c + 1) * 8192;
#pragma unroll
            for (int i = 0; i < 8; ++i) pf[i] = *(const uint4*)(gn + i * 16);
            rpf = Rb[(c + 1) * 64];
        }

        float m = alpha;
#pragma unroll
        for (int off = 1; off < 64; off <<= 1) m = fmaxf(m, __shfl_xor(m, off, 64));
        sV[lane] = __expf(alpha - m);
        float acc = 0.f;
        const float4* sv4 = (const float4*)sV;
#pragma unroll
        for (int i = 0; i < 8; ++i) {
            const uint32_t* gw = (const uint32_t*)&cur[i];
            float4 va = sv4[2 * i], vb = sv4[2 * i + 1];
            acc += va.x * bflo(gw[0]) + va.y * bfhi(gw[0]);
            acc += va.z * bflo(gw[1]) + va.w * bfhi(gw[1]);
            acc += vb.x * bflo(gw[2]) + vb.y * bfhi(gw[2]);
            acc += vb.z * bflo(gw[3]) + vb.w * bfhi(gw[3]);
        }
        alpha = m + __logf(fmaxf(acc, 1e-38f)) + rc;
    }

    {
        float m = alpha;
#pragma unroll
        for (int off = 1; off < 64; off <<= 1) m = fmaxf(m, __shfl_xor(m, off, 64));
        float s = __expf(alpha - m);
#pragma unroll
        for (int off = 1; off < 64; off <<= 1) s += __shfl_xor(s, off, 64);
        if (lane == 0) atomicAdd(out, -(m + __logf(s)) * (1.0f / 64.0f));
    }
}

extern "C" void kernel_launch(void* const* d_in, const int* in_sizes, int n_in,
                              void* d_out, int out_size, void* d_ws, size_t ws_size,
                              hipStream_t stream) {
    const int*   x   = (const int*)d_in[0];
    const float* emb = (const float*)d_in[1];
    const float* Wt  = (const float*)d_in[2];
    const float* sw  = (const float*)d_in[3];
    const float* sb  = (const float*)d_in[4];
    const float* ec  = (const float*)d_in[5];
    const float* vw  = (const float*)d_in[6];
    float* out = (float*)d_out;
    char* ws = (char*)d_ws;

    // Phase-1 region (dead after gemm): A, B, emB, dvec, partials.
    // Phase-2 region (Gc, Rc) ALIASES phase-1 -- chunk runs strictly after gemm.
    __hip_bfloat16* Eg  = (__hip_bfloat16*)ws;                         // 134,217,728 B
    __hip_bfloat16* A   = (__hip_bfloat16*)(ws + 134217728ull);        //   4,194,304 B
    __hip_bfloat16* B   = (__hip_bfloat16*)(ws + 138412032ull);        //   1,048,576 B
    __hip_bfloat16* emB = (__hip_bfloat16*)(ws + 139460608ull);        //   2,097,152 B
    float* dvec         = (float*)(ws + 141557760ull);                 //       1,024 B
    float* partials     = (float*)(ws + 141558784ull);                 //     131,072 B
    __hip_bfloat16* Gc  = (__hip_bfloat16*)(ws + 134217728ull);        //  16,777,216 B (alias)
    float* Rc           = (float*)(ws + 150994944ull);                 //     524,288 B
                                                                       // end 151,519,232

    hipMemsetAsync(out, 0, sizeof(float), stream);

    prep_dk<<<1536, 256, 0, stream>>>(x, emb, Wt, ec, vw, A, B, partials);
    dreduce<<<1, 256, 0, stream>>>(partials, dvec);
    emit_kern<<<NT / 16, 256, 0, stream>>>(x, ec, vw, dvec, emB);
    gemm_kern<<<dim3(NTPAD / 128, NCOLS / 128), 256, 0, stream>>>(A, B, emB, Eg);
    chunk_kern<<<NSEQ * CHUNKS, 64, 0, stream>>>(Eg, Gc, Rc);
    combine_kern<<<NSEQ, 64, 0, stream>>>(Gc, Rc, sw, sb, out);
}

// Round 12
// 222.274 us; speedup vs baseline: 1.0394x; 1.0394x over previous
//
#include <hip/hip_runtime.h>
#include <hip/hip_bf16.h>
#include <stdint.h>

#define NT 16320      // 64 * 255
#define NTPAD 16384
#define KDIM 128      // padded from 100
#define NCOLS 4096    // K*K
#define NSEQ 64
#define TSTEPS 255
#define VOCAB 32000
#define EDIM 100
#define CHUNKS 17
#define CLEN 15       // 17*15 = 255

typedef __attribute__((ext_vector_type(8))) short s8v;
typedef __attribute__((ext_vector_type(4))) float f4v;

__device__ __forceinline__ float bflo(uint32_t u) { return __uint_as_float(u << 16); }
__device__ __forceinline__ float bfhi(uint32_t u) { return __uint_as_float(u & 0xffff0000u); }

// async global->LDS, 16B per lane; lane i writes lds_base + i*16 (wave-uniform base)
__device__ __forceinline__ void load_lds16(const void* g, void* l) {
    __builtin_amdgcn_global_load_lds(
        (const __attribute__((address_space(1))) void*)(uintptr_t)g,
        (__attribute__((address_space(3))) void*)(uintptr_t)l,
        16, 0, 0);
}

// ---------------- fused: prep A+B (blocks 0..1279) + dkern (blocks 1280..1535)
__global__ __launch_bounds__(256) void prep_dk(const int* __restrict__ x,
                                               const float* __restrict__ emb,
                                               const float* __restrict__ Wt,
                                               const float* __restrict__ ec,
                                               const float* __restrict__ vw,
                                               __hip_bfloat16* __restrict__ A,
                                               __hip_bfloat16* __restrict__ B,
                                               float* __restrict__ partials) {
    int bid = blockIdx.x;
    int tid = threadIdx.x;
    if (bid < 1280) {
        int rloc = tid >> 4, q = tid & 15;
        int b = bid * 16 + rloc;
        int c0 = q * 8;
        float vals[8] = {0.f, 0.f, 0.f, 0.f, 0.f, 0.f, 0.f, 0.f};
        __hip_bfloat16* dst;
        if (b < NTPAD) {
            if (b < NT) {
                int n = b / TSTEPS;
                int t = b - n * TSTEPS;
                int tok = x[n * 256 + t];
                const float* er = emb + (size_t)tok * EDIM;
#pragma unroll
                for (int i = 0; i < 8; ++i) { int e = c0 + i; if (e < EDIM) vals[i] = er[e]; }
            }
            dst = A + (size_t)b * KDIM + c0;
        } else {
            int cc = b - NTPAD;
            const float* wr = Wt + (size_t)cc * EDIM;
#pragma unroll
            for (int i = 0; i < 8; ++i) { int e = c0 + i; if (e < EDIM) vals[i] = wr[e]; }
            dst = B + (size_t)cc * KDIM + c0;
        }
        union { __hip_bfloat16 h[8]; uint4 u; } pk;
#pragma unroll
        for (int i = 0; i < 8; ++i) pk.h[i] = __float2bfloat16(vals[i]);
        *(uint4*)dst = pk.u;
    } else {
        int db = bid - 1280;
        int wave = tid >> 6, lane = tid & 63;
        float er[64];
        {
            const float4* ecv = (const float4*)(ec + (size_t)lane * 64);
#pragma unroll
            for (int i = 0; i < 16; ++i) {
                float4 v = ecv[i];
                er[4 * i] = v.x; er[4 * i + 1] = v.y; er[4 * i + 2] = v.z; er[4 * i + 3] = v.w;
            }
        }
        int v0 = db * 125;
        float m = -1e30f, s = 0.f;
        for (int v = v0 + wave; v < v0 + 125; v += 4) {
            int vu = __builtin_amdgcn_readfirstlane(v);
            const float* row = vw + (size_t)vu * 64;
            float acc = 0.f;
#pragma unroll
            for (int e = 0; e < 64; ++e) acc += er[e] * row[e];
            float nm = fmaxf(m, acc);
            s = s * __expf(m - nm) + __expf(acc - nm);
            m = nm;
        }
        __shared__ float pm[4][64], ps[4][64];
        pm[wave][lane] = m; ps[wave][lane] = s;
        __syncthreads();
        if (tid < 64) {
            float M = pm[0][tid], Ssum = ps[0][tid];
#pragma unroll
            for (int w = 1; w < 4; ++w) {
                float m2 = pm[w][tid], s2 = ps[w][tid];
                float nm = fmaxf(M, m2);
                Ssum = Ssum * __expf(M - nm) + s2 * __expf(m2 - nm);
                M = nm;
            }
            partials[(db * 64 + tid) * 2]     = M;
            partials[(db * 64 + tid) * 2 + 1] = Ssum;
        }
    }
}

__global__ __launch_bounds__(256) void dreduce(const float* __restrict__ partials,
                                               float* __restrict__ d) {
    __shared__ float pm[4][64], ps[4][64];
    int k = threadIdx.x & 63, part = threadIdx.x >> 6;
    float M = -1e30f, S = 0.f;
    for (int b = part; b < 256; b += 4) {
        float m2 = partials[(b * 64 + k) * 2];
        float s2 = partials[(b * 64 + k) * 2 + 1];
        float nm = fmaxf(M, m2);
        S = S * __expf(M - nm) + s2 * __expf(m2 - nm);
        M = nm;
    }
    pm[part][k] = M; ps[part][k] = S;
    __syncthreads();
    if (threadIdx.x < 64) {
        float Mm = pm[0][k], Ss = ps[0][k];
#pragma unroll
        for (int w = 1; w < 4; ++w) {
            float m2 = pm[w][k], s2 = ps[w][k];
            float nm = fmaxf(Mm, m2);
            Ss = Ss * __expf(Mm - nm) + s2 * __expf(m2 - nm);
            Mm = nm;
        }
        d[k] = Mm + __logf(Ss);
    }
}

// ---------------- emissions: register-cached ec, 4 tokens/wave ----------------
// pos(j) = ((j>>2)&3)*16 + ((j>>4)&3)*4 + (j&3)
__global__ __launch_bounds__(256) void emit_kern(const int* __restrict__ x,
                                                 const float* __restrict__ ec,
                                                 const float* __restrict__ vw,
                                                 const float* __restrict__ d,
                                                 __hip_bfloat16* __restrict__ emB) {
    int tid = threadIdx.x;
    int wave = tid >> 6, lane = tid & 63;
    float er[64];
    {
        const float4* ecv = (const float4*)(ec + (size_t)lane * 64);
#pragma unroll
        for (int i = 0; i < 16; ++i) {
            float4 v = ecv[i];
            er[4 * i] = v.x; er[4 * i + 1] = v.y; er[4 * i + 2] = v.z; er[4 * i + 3] = v.w;
        }
    }
    float dj = d[lane];
    int j = lane;
    int pos = ((j >> 2) & 3) * 16 + ((j >> 4) & 3) * 4 + (j & 3);
    int nt0 = blockIdx.x * 16 + wave * 4;     // grid 1020 -> 16320 exactly
#pragma unroll
    for (int s = 0; s < 4; ++s) {
        int nt = nt0 + s;
        int n = nt / TSTEPS;
        int t = nt - n * TSTEPS;
        int tok = x[n * 256 + t + 1];
        tok = __builtin_amdgcn_readfirstlane(tok);
        const float* row = vw + (size_t)tok * 64;
        float acc = 0.f;
#pragma unroll
        for (int e = 0; e < 64; ++e) acc += er[e] * row[e];
        emB[(size_t)nt * 64 + pos] = __float2bfloat16(__expf(acc - dj));
    }
}

// ---------------- GEMM (transposed) + softmax*em -> bf16 E --------------------
// 128 m x 64 c tiles (one full i-group per block): LDS 48 KB -> 3 blocks/CU.
// Wave w: m-range [w*32,+32) x all 64 c. Softmax over j = 16 in-lane + xor16/32.
__global__ __launch_bounds__(256) void gemm_kern(const __hip_bfloat16* __restrict__ A,
                                                 const __hip_bfloat16* __restrict__ B,
                                                 const __hip_bfloat16* __restrict__ emB,
                                                 __hip_bfloat16* __restrict__ Eg) {
    int mblk = blockIdx.x;   // 0..127 (128 m rows)
    int nblk = blockIdx.y;   // 0..63  (64 c cols = i-group nblk)
    int tid = threadIdx.x, wave = tid >> 6, lane = tid & 63;

    __shared__ __align__(16) char smem[49152];
    char* sA = smem;            // 128 m-rows * 256 B = 32768
    char* sB = smem + 32768;    // 64 c-rows * 256 B = 16384

    // ---- stage: wave w loads A rows [w*32,+32), B rows [w*16,+16) ----
    {
        int l16 = lane & 15;
        int rsub = lane >> 4;
#pragma unroll
        for (int g = 0; g < 8; ++g) {
            int r = wave * 32 + g * 4 + rsub;
            int chunk = l16 ^ (r & 7);
            const char* gp = (const char*)(A + (size_t)(mblk * 128 + r) * KDIM) + chunk * 16;
            load_lds16(gp, sA + (wave * 32 + g * 4) * 256);
        }
#pragma unroll
        for (int g = 0; g < 4; ++g) {
            int r = wave * 16 + g * 4 + rsub;
            int chunk = l16 ^ (r & 7);
            const char* gp = (const char*)(B + (size_t)(nblk * 64 + r) * KDIM) + chunk * 16;
            load_lds16(gp, sB + (wave * 16 + g * 4) * 256);
        }
    }
    __syncthreads();

    // ---- compute: A-operand = W rows (c), B-operand = xe rows (m) ----
    int wm = wave * 32;
    int l15 = lane & 15, g4 = lane >> 4;
    f4v acc[4][2] = {};   // [jt(c-tile)][mt(m-tile)]
#pragma unroll
    for (int k32 = 0; k32 < 4; ++k32) {
        s8v af[4], bf[2];
#pragma unroll
        for (int jt = 0; jt < 4; ++jt) {
            int r = jt * 16 + l15;
            int chunk = (k32 * 4 + g4) ^ (r & 7);
            af[jt] = *(const s8v*)(sB + r * 256 + chunk * 16);
        }
#pragma unroll
        for (int mt = 0; mt < 2; ++mt) {
            int r = wm + mt * 16 + l15;
            int chunk = (k32 * 4 + g4) ^ (r & 7);
            bf[mt] = *(const s8v*)(sA + r * 256 + chunk * 16);
        }
#pragma unroll
        for (int jt = 0; jt < 4; ++jt)
#pragma unroll
            for (int mt = 0; mt < 2; ++mt)
                acc[jt][mt] = __builtin_amdgcn_mfma_f32_16x16x32_bf16(af[jt], bf[mt], acc[jt][mt], 0, 0, 0);
    }
    __syncthreads();   // staging dead; reuse for sW

    // ---- epilogue: per col m: softmax over 64 j, * em, bf16 pack -> sW ----
    char* sW = smem;   // 128 m-rows * 136 B (128 data + 8 pad)
    const char* emb8 = (const char*)emB;
#pragma unroll
    for (int mt = 0; mt < 2; ++mt) {
        int mrow = wm + mt * 16 + l15;
        int mglob = mblk * 128 + mrow;
        float v[16];
#pragma unroll
        for (int jt = 0; jt < 4; ++jt)
#pragma unroll
            for (int rr = 0; rr < 4; ++rr) v[jt * 4 + rr] = acc[jt][mt][rr];
        float mx = v[0];
#pragma unroll
        for (int k = 1; k < 16; ++k) mx = fmaxf(mx, v[k]);
        mx = fmaxf(mx, __shfl_xor(mx, 16, 64));
        mx = fmaxf(mx, __shfl_xor(mx, 32, 64));
        float ex[16], sg = 0.f;
#pragma unroll
        for (int k = 0; k < 16; ++k) { ex[k] = __expf(v[k] - mx); sg += ex[k]; }
        sg += __shfl_xor(sg, 16, 64);
        sg += __shfl_xor(sg, 32, 64);
        float inv = 1.0f / sg;
        // j = jt*16 + g4*4 + rr  ->  pos = g4*16 + jt*4 + rr: 16 contiguous at g4*16
        uint4 e0 = *(const uint4*)(emb8 + (size_t)mglob * 128 + g4 * 32);
        uint4 e1 = *(const uint4*)(emb8 + (size_t)mglob * 128 + g4 * 32 + 16);
        float em[16];
        {
            const uint32_t* w0 = (const uint32_t*)&e0;
            const uint32_t* w1 = (const uint32_t*)&e1;
#pragma unroll
            for (int i = 0; i < 4; ++i) {
                em[2 * i] = bflo(w0[i]);     em[2 * i + 1] = bfhi(w0[i]);
                em[8 + 2 * i] = bflo(w1[i]); em[8 + 2 * i + 1] = bfhi(w1[i]);
            }
        }
        // em index for j at (jt,rr): pos-permuted load gives em[jt*4+rr] <-> ex[jt*4+rr]
#pragma unroll
        for (int jt = 0; jt < 4; ++jt) {
            union { __hip_bfloat16 h[4]; uint2 u; } pk;
#pragma unroll
            for (int rr = 0; rr < 4; ++rr)
                pk.h[rr] = __float2bfloat16(ex[jt * 4 + rr] * inv * em[jt * 4 + rr]);
            *(uint2*)(sW + mrow * 136 + (jt * 16 + g4 * 4) * 2) = pk.u;
        }
    }
    __syncthreads();

    // ---- coalesced store: per wave-instruction 8 rows x 128 B contiguous ----
    {
        int rloc = lane >> 3;         // 0..7
        int q = lane & 7;             // 16 B chunk within 128 B
#pragma unroll
        for (int rp = 0; rp < 4; ++rp) {
            int row = wave * 32 + rp * 8 + rloc;
            int m = mblk * 128 + row;
            if (m < NT) {
                char* dst = (char*)Eg + (size_t)m * 8192 + nblk * 128;
                *(uint4*)(dst + q * 16) = *(const uint4*)(sW + row * 136 + q * 16);
            }
        }
    }
}

// ---------------- chunk: one wave per chunk (15 steps), barrier-free, bf16 ----
__global__ __launch_bounds__(64) void chunk_kern(const __hip_bfloat16* __restrict__ Eg,
                                                 __hip_bfloat16* __restrict__ Gout,
                                                 float* __restrict__ Rout) {
    int lane = threadIdx.x;
    int l15 = lane & 15, g4 = lane >> 4;
    int id = blockIdx.x;               // 0..1087
    int n = (id * 3856) >> 16;         // id / 17 (magic, exact for id < 4096)
    int c = id - n * 17;
    int base_m = n * TSTEPS + c * CLEN;

    __shared__ __align__(16) char sGT[64 * 144];   // 9216 B

    // init identity: lane owns row (= column) `lane`
    {
        uint4 z = {0, 0, 0, 0};
#pragma unroll
        for (int i = 0; i < 8; ++i) *(uint4*)(sGT + lane * 144 + i * 16) = z;
        *(uint16_t*)(sGT + lane * 144 + lane * 2) = 0x3F80;   // bf16 1.0
    }

    const char* Ebase = (const char*)Eg;
    uint4 pf[4][2];
    {
        const char* tp = Ebase + (size_t)(base_m + 14) * 8192;
#pragma unroll
        for (int at = 0; at < 4; ++at)
#pragma unroll
            for (int kk = 0; kk < 2; ++kk)
                pf[at][kk] = *(const uint4*)(tp + (at * 16 + l15) * 128 + kk * 64 + g4 * 16);
    }

    float rlog[4] = {0.f, 0.f, 0.f, 0.f};

    for (int tl = 14; tl >= 0; --tl) {
        uint4 af[4][2];
#pragma unroll
        for (int at = 0; at < 4; ++at) { af[at][0] = pf[at][0]; af[at][1] = pf[at][1]; }
        if (tl > 0) {
            const char* tp = Ebase + (size_t)(base_m + tl - 1) * 8192;
#pragma unroll
            for (int at = 0; at < 4; ++at)
#pragma unroll
                for (int kk = 0; kk < 2; ++kk)
                    pf[at][kk] = *(const uint4*)(tp + (at * 16 + l15) * 128 + kk * 64 + g4 * 16);
        }

        f4v acc[4][4] = {};   // [at(m-tile)][ct(n-tile)]
#pragma unroll
        for (int kk = 0; kk < 2; ++kk) {
#pragma unroll
            for (int ct = 0; ct < 4; ++ct) {
                s8v b = *(const s8v*)(sGT + (ct * 16 + l15) * 144 + kk * 64 + g4 * 16);
#pragma unroll
                for (int at = 0; at < 4; ++at)
                    acc[at][ct] = __builtin_amdgcn_mfma_f32_16x16x32_bf16(
                        *(const s8v*)&af[at][kk], b, acc[at][ct], 0, 0, 0);
            }
        }

        // colmax-normalize per ct (col = ct*16 + l15)
#pragma unroll
        for (int ct = 0; ct < 4; ++ct) {
            float mx = acc[0][ct][0];
#pragma unroll
            for (int at = 0; at < 4; ++at)
#pragma unroll
                for (int rr = 0; rr < 4; ++rr) mx = fmaxf(mx, acc[at][ct][rr]);
            mx = fmaxf(mx, __shfl_xor(mx, 16, 64));
            mx = fmaxf(mx, __shfl_xor(mx, 32, 64));
            mx = fmaxf(mx, 1e-38f);
            rlog[ct] += __logf(mx);
            float inv = 1.0f / mx;
            int col = ct * 16 + l15;
#pragma unroll
            for (int at = 0; at < 4; ++at) {
                union { __hip_bfloat16 h[4]; uint2 u; } pk;
#pragma unroll
                for (int rr = 0; rr < 4; ++rr)
                    pk.h[rr] = __float2bfloat16(acc[at][ct][rr] * inv);
                *(uint2*)(sGT + col * 144 + at * 32 + g4 * 8) = pk.u;
            }
        }
    }

    // ---- output: Gout[id*4096 + c*64 + a] = W[a][c]; lane -> col = lane ----
    {
        char* go = (char*)(Gout + (size_t)id * 4096 + lane * 64);
#pragma unroll
        for (int i = 0; i < 8; ++i)
            *(uint4*)(go + i * 16) = *(const uint4*)(sGT + lane * 144 + i * 16);
    }
    if (g4 == 0)
#pragma unroll
        for (int ct = 0; ct < 4; ++ct)
            Rout[(size_t)id * 64 + ct * 16 + l15] = rlog[ct];
}

// ---------------- combine: ONE WAVE per sequence, barrier-free ----------------
__global__ __launch_bounds__(64) void combine_kern(const __hip_bfloat16* __restrict__ G,
                                                   const float* __restrict__ R,
                                                   const float* __restrict__ sw,
                                                   const float* __restrict__ sb,
                                                   float* __restrict__ out) {
    int n = blockIdx.x;
    int lane = threadIdx.x;
    __shared__ __align__(16) float sV[64];

    float alpha;
    {
        float v = sw[lane] + sb[lane];
        float m = v;
#pragma unroll
        for (int off = 1; off < 64; off <<= 1) m = fmaxf(m, __shfl_xor(m, off, 64));
        float s = __expf(v - m);
#pragma unroll
        for (int off = 1; off < 64; off <<= 1) s += __shfl_xor(s, off, 64);
        alpha = v - (m + __logf(s));
    }

    const char* Gb = (const char*)(G + (size_t)n * CHUNKS * 4096) + lane * 128;
    const float* Rb = R + (size_t)n * CHUNKS * 64 + lane;

    uint4 pf[8];
#pragma unroll
    for (int i = 0; i < 8; ++i) pf[i] = *(const uint4*)(Gb + i * 16);
    float rpf = Rb[0];

    for (int c = 0; c < CHUNKS; ++c) {
        uint4 cur[8];
#pragma unroll
        for (int i = 0; i < 8; ++i) cur[i] = pf[i];
        float rc = rpf;
        if (c + 1 < CHUNKS) {
            const char* gn = Gb + (size_t)(c + 1) * 8192;
#pragma unroll
            for (int i = 0; i < 8; ++i) pf[i] = *(const uint4*)(gn + i * 16);
            rpf = Rb[(c + 1) * 64];
        }

        float m = alpha;
#pragma unroll
        for (int off = 1; off < 64; off <<= 1) m = fmaxf(m, __shfl_xor(m, off, 64));
        sV[lane] = __expf(alpha - m);
        float acc = 0.f;
        const float4* sv4 = (const float4*)sV;
#pragma unroll
        for (int i = 0; i < 8; ++i) {
            const uint32_t* gw = (const uint32_t*)&cur[i];
            float4 va = sv4[2 * i], vb = sv4[2 * i + 1];
            acc += va.x * bflo(gw[0]) + va.y * bfhi(gw[0]);
            acc += va.z * bflo(gw[1]) + va.w * bfhi(gw[1]);
            acc += vb.x * bflo(gw[2]) + vb.y * bfhi(gw[2]);
            acc += vb.z * bflo(gw[3]) + vb.w * bfhi(gw[3]);
        }
        alpha = m + __logf(fmaxf(acc, 1e-38f)) + rc;
    }

    {
        float m = alpha;
#pragma unroll
        for (int off = 1; off < 64; off <<= 1) m = fmaxf(m, __shfl_xor(m, off, 64));
        float s = __expf(alpha - m);
#pragma unroll
        for (int off = 1; off < 64; off <<= 1) s += __shfl_xor(s, off, 64);
        if (lane == 0) atomicAdd(out, -(m + __logf(s)) * (1.0f / 64.0f));
    }
}

extern "C" void kernel_launch(void* const* d_in, const int* in_sizes, int n_in,
                              void* d_out, int out_size, void* d_ws, size_t ws_size,
                              hipStream_t stream) {
    const int*   x   = (const int*)d_in[0];
    const float* emb = (const float*)d_in[1];
    const float* Wt  = (const float*)d_in[2];
    const float* sw  = (const float*)d_in[3];
    const float* sb  = (const float*)d_in[4];
    const float* ec  = (const float*)d_in[5];
    const float* vw  = (const float*)d_in[6];
    float* out = (float*)d_out;
    char* ws = (char*)d_ws;

    __hip_bfloat16* Eg  = (__hip_bfloat16*)ws;                         // 134,217,728 B
    __hip_bfloat16* A   = (__hip_bfloat16*)(ws + 134217728ull);        //   4,194,304 B
    __hip_bfloat16* B   = (__hip_bfloat16*)(ws + 138412032ull);        //   1,048,576 B
    __hip_bfloat16* emB = (__hip_bfloat16*)(ws + 139460608ull);        //   2,097,152 B
    float* dvec         = (float*)(ws + 141557760ull);                 //       1,024 B
    float* partials     = (float*)(ws + 141558784ull);                 //     131,072 B
    __hip_bfloat16* Gc  = (__hip_bfloat16*)(ws + 141689856ull);        //   8,912,896 B
    float* Rc           = (float*)(ws + 150602752ull);                 //     278,528 B
                                                                       // end 150,881,280

    hipMemsetAsync(out, 0, sizeof(float), stream);

    prep_dk<<<1536, 256, 0, stream>>>(x, emb, Wt, ec, vw, A, B, partials);
    dreduce<<<1, 256, 0, stream>>>(partials, dvec);
    emit_kern<<<NT / 16, 256, 0, stream>>>(x, ec, vw, dvec, emB);
    gemm_kern<<<dim3(NTPAD / 128, NCOLS / 64), 256, 0, stream>>>(A, B, emB, Eg);
    chunk_kern<<<NSEQ * CHUNKS, 64, 0, stream>>>(Eg, Gc, Rc);
    combine_kern<<<NSEQ, 64, 0, stream>>>(Gc, Rc, sw, sb, out);
}

// Round 13
// 213.676 us; speedup vs baseline: 1.0813x; 1.0402x over previous
//
#include <hip/hip_runtime.h>
#include <hip/hip_bf16.h>
#include <stdint.h>

#define NT 16320      // 64 * 255
#define NTPAD 16384
#define KDIM 128      // padded from 100
#define NCOLS 4096    // K*K
#define NSEQ 64
#define TSTEPS 255
#define VOCAB 32000
#define EDIM 100
#define CHUNKS 17
#define CLEN 15       // 17*15 = 255

typedef __attribute__((ext_vector_type(8))) short s8v;
typedef __attribute__((ext_vector_type(4))) float f4v;

__device__ __forceinline__ float bflo(uint32_t u) { return __uint_as_float(u << 16); }
__device__ __forceinline__ float bfhi(uint32_t u) { return __uint_as_float(u & 0xffff0000u); }

// async global->LDS, 16B per lane; lane i writes lds_base + i*16 (wave-uniform base)
__device__ __forceinline__ void load_lds16(const void* g, void* l) {
    __builtin_amdgcn_global_load_lds(
        (const __attribute__((address_space(1))) void*)(uintptr_t)g,
        (__attribute__((address_space(3))) void*)(uintptr_t)l,
        16, 0, 0);
}

// ---------------- fused: prep A+B (blocks 0..1279) + dkern (blocks 1280..1535)
__global__ __launch_bounds__(256) void prep_dk(const int* __restrict__ x,
                                               const float* __restrict__ emb,
                                               const float* __restrict__ Wt,
                                               const float* __restrict__ ec,
                                               const float* __restrict__ vw,
                                               __hip_bfloat16* __restrict__ A,
                                               __hip_bfloat16* __restrict__ B,
                                               float* __restrict__ partials) {
    int bid = blockIdx.x;
    int tid = threadIdx.x;
    if (bid < 1280) {
        int rloc = tid >> 4, q = tid & 15;
        int b = bid * 16 + rloc;
        int c0 = q * 8;
        float vals[8] = {0.f, 0.f, 0.f, 0.f, 0.f, 0.f, 0.f, 0.f};
        __hip_bfloat16* dst;
        if (b < NTPAD) {
            if (b < NT) {
                int n = b / TSTEPS;
                int t = b - n * TSTEPS;
                int tok = x[n * 256 + t];
                const float* er = emb + (size_t)tok * EDIM;
#pragma unroll
                for (int i = 0; i < 8; ++i) { int e = c0 + i; if (e < EDIM) vals[i] = er[e]; }
            }
            dst = A + (size_t)b * KDIM + c0;
        } else {
            int cc = b - NTPAD;
            const float* wr = Wt + (size_t)cc * EDIM;
#pragma unroll
            for (int i = 0; i < 8; ++i) { int e = c0 + i; if (e < EDIM) vals[i] = wr[e]; }
            dst = B + (size_t)cc * KDIM + c0;
        }
        union { __hip_bfloat16 h[8]; uint4 u; } pk;
#pragma unroll
        for (int i = 0; i < 8; ++i) pk.h[i] = __float2bfloat16(vals[i]);
        *(uint4*)dst = pk.u;
    } else {
        int db = bid - 1280;
        int wave = tid >> 6, lane = tid & 63;
        float er[64];
        {
            const float4* ecv = (const float4*)(ec + (size_t)lane * 64);
#pragma unroll
            for (int i = 0; i < 16; ++i) {
                float4 v = ecv[i];
                er[4 * i] = v.x; er[4 * i + 1] = v.y; er[4 * i + 2] = v.z; er[4 * i + 3] = v.w;
            }
        }
        int v0 = db * 125;
        float m = -1e30f, s = 0.f;
        for (int v = v0 + wave; v < v0 + 125; v += 4) {
            int vu = __builtin_amdgcn_readfirstlane(v);
            const float* row = vw + (size_t)vu * 64;
            float acc = 0.f;
#pragma unroll
            for (int e = 0; e < 64; ++e) acc += er[e] * row[e];
            float nm = fmaxf(m, acc);
            s = s * __expf(m - nm) + __expf(acc - nm);
            m = nm;
        }
        __shared__ float pm[4][64], ps[4][64];
        pm[wave][lane] = m; ps[wave][lane] = s;
        __syncthreads();
        if (tid < 64) {
            float M = pm[0][tid], Ssum = ps[0][tid];
#pragma unroll
            for (int w = 1; w < 4; ++w) {
                float m2 = pm[w][tid], s2 = ps[w][tid];
                float nm = fmaxf(M, m2);
                Ssum = Ssum * __expf(M - nm) + s2 * __expf(m2 - nm);
                M = nm;
            }
            partials[(db * 64 + tid) * 2]     = M;
            partials[(db * 64 + tid) * 2 + 1] = Ssum;
        }
    }
}

// ---------------- emissions (dreduce inlined): 8 tokens/wave ------------------
// pos(j) = ((j>>2)&3)*16 + ((j>>4)&3)*4 + (j&3)
__global__ __launch_bounds__(256) void emit_kern(const int* __restrict__ x,
                                                 const float* __restrict__ ec,
                                                 const float* __restrict__ vw,
                                                 const float* __restrict__ partials,
                                                 __hip_bfloat16* __restrict__ emB) {
    __shared__ float pm[4][64], ps[4][64], sD[64];
    int tid = threadIdx.x;
    int wave = tid >> 6, lane = tid & 63;

    // inline dreduce: (wave, lane) reduces partials rows b = wave, wave+4, ...
    {
        float M = -1e30f, S = 0.f;
        for (int b = wave; b < 256; b += 4) {
            float m2 = partials[(b * 64 + lane) * 2];
            float s2 = partials[(b * 64 + lane) * 2 + 1];
            float nm = fmaxf(M, m2);
            S = S * __expf(M - nm) + s2 * __expf(m2 - nm);
            M = nm;
        }
        pm[wave][lane] = M; ps[wave][lane] = S;
    }

    float er[64];
    {
        const float4* ecv = (const float4*)(ec + (size_t)lane * 64);
#pragma unroll
        for (int i = 0; i < 16; ++i) {
            float4 v = ecv[i];
            er[4 * i] = v.x; er[4 * i + 1] = v.y; er[4 * i + 2] = v.z; er[4 * i + 3] = v.w;
        }
    }
    __syncthreads();
    if (tid < 64) {
        float M = pm[0][tid], S = ps[0][tid];
#pragma unroll
        for (int w = 1; w < 4; ++w) {
            float m2 = pm[w][tid], s2 = ps[w][tid];
            float nm = fmaxf(M, m2);
            S = S * __expf(M - nm) + s2 * __expf(m2 - nm);
            M = nm;
        }
        sD[tid] = M + __logf(S);
    }
    __syncthreads();

    float dj = sD[lane];
    int j = lane;
    int pos = ((j >> 2) & 3) * 16 + ((j >> 4) & 3) * 4 + (j & 3);
    int nt0 = blockIdx.x * 32 + wave * 8;     // grid 510 -> 16320 exactly
#pragma unroll
    for (int s = 0; s < 8; ++s) {
        int nt = nt0 + s;
        int n = nt / TSTEPS;
        int t = nt - n * TSTEPS;
        int tok = x[n * 256 + t + 1];
        tok = __builtin_amdgcn_readfirstlane(tok);
        const float* row = vw + (size_t)tok * 64;
        float acc = 0.f;
#pragma unroll
        for (int e = 0; e < 64; ++e) acc += er[e] * row[e];
        emB[(size_t)nt * 64 + pos] = __float2bfloat16(__expf(acc - dj));
    }
}

// ---------------- GEMM (transposed) + softmax*em -> bf16 E --------------------
// 128x128 tile (R10 version, measured 53.0 us).
__global__ __launch_bounds__(256) void gemm_kern(const __hip_bfloat16* __restrict__ A,
                                                 const __hip_bfloat16* __restrict__ B,
                                                 const __hip_bfloat16* __restrict__ emB,
                                                 __hip_bfloat16* __restrict__ Eg) {
    int mblk = blockIdx.x;   // 0..127 (128 m rows)
    int nblk = blockIdx.y;   // 0..31  (128 c cols)
    int tid = threadIdx.x, wave = tid >> 6, lane = tid & 63;

    __shared__ __align__(16) char smem[65536];
    char* sA = smem;            // 128 m-rows * 256 B
    char* sB = smem + 32768;    // 128 c-rows * 256 B

    // ---- stage ----
    {
        int r0 = wave * 32;
        int l16 = lane & 15;
        int rsub = lane >> 4;
#pragma unroll
        for (int g = 0; g < 8; ++g) {
            int r = r0 + g * 4 + rsub;
            int chunk = l16 ^ (r & 7);
            const char* gp = (const char*)(A + (size_t)(mblk * 128 + r) * KDIM) + chunk * 16;
            load_lds16(gp, sA + (r0 + g * 4) * 256);
        }
#pragma unroll
        for (int g = 0; g < 8; ++g) {
            int c = r0 + g * 4 + rsub;
            int chunk = l16 ^ (c & 7);
            const char* gp = (const char*)(B + (size_t)(nblk * 128 + c) * KDIM) + chunk * 16;
            load_lds16(gp, sB + (r0 + g * 4) * 256);
        }
    }
    __syncthreads();

    // ---- compute: A-operand = W rows (c), B-operand = xe rows (m) ----
    int wc = (wave >> 1) * 64, wm = (wave & 1) * 64;
    int l15 = lane & 15, g4 = lane >> 4;
    f4v acc[4][4] = {};   // [jt(c-tile)][mt(m-tile)]
#pragma unroll
    for (int k32 = 0; k32 < 4; ++k32) {
        s8v af[4], bf[4];
#pragma unroll
        for (int jt = 0; jt < 4; ++jt) {
            int r = wc + jt * 16 + l15;
            int chunk = (k32 * 4 + g4) ^ (r & 7);
            af[jt] = *(const s8v*)(sB + r * 256 + chunk * 16);
        }
#pragma unroll
        for (int mt = 0; mt < 4; ++mt) {
            int r = wm + mt * 16 + l15;
            int chunk = (k32 * 4 + g4) ^ (r & 7);
            bf[mt] = *(const s8v*)(sA + r * 256 + chunk * 16);
        }
#pragma unroll
        for (int jt = 0; jt < 4; ++jt)
#pragma unroll
            for (int mt = 0; mt < 4; ++mt)
                acc[jt][mt] = __builtin_amdgcn_mfma_f32_16x16x32_bf16(af[jt], bf[mt], acc[jt][mt], 0, 0, 0);
    }
    __syncthreads();   // staging dead; reuse for sW

    // ---- epilogue: per col m: softmax over 64 j, * em, bf16 pack -> sW ----
    char* sW = smem;   // 128 m-rows * 272 B (256 data + 16 pad)
    const char* emb8 = (const char*)emB;
#pragma unroll
    for (int mt = 0; mt < 4; ++mt) {
        int mrow = wm + mt * 16 + l15;
        int mglob = mblk * 128 + mrow;
        float v[16];
#pragma unroll
        for (int jt = 0; jt < 4; ++jt)
#pragma unroll
            for (int rr = 0; rr < 4; ++rr) v[jt * 4 + rr] = acc[jt][mt][rr];
        float mx = v[0];
#pragma unroll
        for (int k = 1; k < 16; ++k) mx = fmaxf(mx, v[k]);
        mx = fmaxf(mx, __shfl_xor(mx, 16, 64));
        mx = fmaxf(mx, __shfl_xor(mx, 32, 64));
        float ex[16], sg = 0.f;
#pragma unroll
        for (int k = 0; k < 16; ++k) { ex[k] = __expf(v[k] - mx); sg += ex[k]; }
        sg += __shfl_xor(sg, 16, 64);
        sg += __shfl_xor(sg, 32, 64);
        float inv = 1.0f / sg;
        uint4 e0 = *(const uint4*)(emb8 + (size_t)mglob * 128 + g4 * 32);
        uint4 e1 = *(const uint4*)(emb8 + (size_t)mglob * 128 + g4 * 32 + 16);
        float em[16];
        {
            const uint32_t* w0 = (const uint32_t*)&e0;
            const uint32_t* w1 = (const uint32_t*)&e1;
#pragma unroll
            for (int i = 0; i < 4; ++i) {
                em[2 * i] = bflo(w0[i]);     em[2 * i + 1] = bfhi(w0[i]);
                em[8 + 2 * i] = bflo(w1[i]); em[8 + 2 * i + 1] = bfhi(w1[i]);
            }
        }
#pragma unroll
        for (int jt = 0; jt < 4; ++jt) {
            union { __hip_bfloat16 h[4]; uint2 u; } pk;
#pragma unroll
            for (int rr = 0; rr < 4; ++rr)
                pk.h[rr] = __float2bfloat16(ex[jt * 4 + rr] * inv * em[jt * 4 + rr]);
            *(uint2*)(sW + mrow * 272 + (wc + jt * 16 + g4 * 4) * 2) = pk.u;
        }
    }
    __syncthreads();

    // ---- coalesced store: per wave-instruction 8 rows x 128 B contiguous ----
    {
        int rloc = tid >> 3;          // 0..31
        int q = tid & 7;              // 16 B chunk within 128 B half
#pragma unroll
        for (int rp = 0; rp < 4; ++rp) {
            int row = rp * 32 + rloc;
            char* dst = (char*)Eg + (size_t)(mblk * 128 + row) * 8192 + nblk * 256;
            const char* src = sW + row * 272;
            *(uint4*)(dst + q * 16)       = *(const uint4*)(src + q * 16);
            *(uint4*)(dst + 128 + q * 16) = *(const uint4*)(src + 128 + q * 16);
        }
    }
}

// ---------------- chunk: one wave per chunk, norm every 3 steps ---------------
__global__ __launch_bounds__(64) void chunk_kern(const __hip_bfloat16* __restrict__ Eg,
                                                 __hip_bfloat16* __restrict__ Gout,
                                                 float* __restrict__ Rout,
                                                 float* __restrict__ out) {
    int lane = threadIdx.x;
    if (blockIdx.x == 0 && lane == 0) *out = 0.f;   // zero for combine's atomics
    int l15 = lane & 15, g4 = lane >> 4;
    int id = blockIdx.x;               // 0..1087
    int n = (id * 3856) >> 16;         // id / 17 (magic, exact for id < 4096)
    int c = id - n * 17;
    int base_m = n * TSTEPS + c * CLEN;

    __shared__ __align__(16) char sGT[64 * 144];   // 9216 B

    // init identity: lane owns row (= column) `lane`
    {
        uint4 z = {0, 0, 0, 0};
#pragma unroll
        for (int i = 0; i < 8; ++i) *(uint4*)(sGT + lane * 144 + i * 16) = z;
        *(uint16_t*)(sGT + lane * 144 + lane * 2) = 0x3F80;   // bf16 1.0
    }

    const char* Ebase = (const char*)Eg;
    uint4 pf[4][2];
    {
        const char* tp = Ebase + (size_t)(base_m + 14) * 8192;
#pragma unroll
        for (int at = 0; at < 4; ++at)
#pragma unroll
            for (int kk = 0; kk < 2; ++kk)
                pf[at][kk] = *(const uint4*)(tp + (at * 16 + l15) * 128 + kk * 64 + g4 * 16);
    }

    float rlog[4] = {0.f, 0.f, 0.f, 0.f};

    for (int tl = 14; tl >= 0; --tl) {
        uint4 af[4][2];
#pragma unroll
        for (int at = 0; at < 4; ++at) { af[at][0] = pf[at][0]; af[at][1] = pf[at][1]; }
        if (tl > 0) {
            const char* tp = Ebase + (size_t)(base_m + tl - 1) * 8192;
#pragma unroll
            for (int at = 0; at < 4; ++at)
#pragma unroll
                for (int kk = 0; kk < 2; ++kk)
                    pf[at][kk] = *(const uint4*)(tp + (at * 16 + l15) * 128 + kk * 64 + g4 * 16);
        }

        f4v acc[4][4] = {};   // [at(m-tile)][ct(n-tile)]
#pragma unroll
        for (int kk = 0; kk < 2; ++kk) {
#pragma unroll
            for (int ct = 0; ct < 4; ++ct) {
                s8v b = *(const s8v*)(sGT + (ct * 16 + l15) * 144 + kk * 64 + g4 * 16);
#pragma unroll
                for (int at = 0; at < 4; ++at)
                    acc[at][ct] = __builtin_amdgcn_mfma_f32_16x16x32_bf16(
                        *(const s8v*)&af[at][kk], b, acc[at][ct], 0, 0, 0);
            }
        }

        if (tl % 3 == 0) {
            // full colmax-normalize (bf16 exponent absorbs <=3 steps of decay)
#pragma unroll
            for (int ct = 0; ct < 4; ++ct) {
                float mx = acc[0][ct][0];
#pragma unroll
                for (int at = 0; at < 4; ++at)
#pragma unroll
                    for (int rr = 0; rr < 4; ++rr) mx = fmaxf(mx, acc[at][ct][rr]);
                mx = fmaxf(mx, __shfl_xor(mx, 16, 64));
                mx = fmaxf(mx, __shfl_xor(mx, 32, 64));
                mx = fmaxf(mx, 1e-38f);
                rlog[ct] += __logf(mx);
                float inv = 1.0f / mx;
                int col = ct * 16 + l15;
#pragma unroll
                for (int at = 0; at < 4; ++at) {
                    union { __hip_bfloat16 h[4]; uint2 u; } pk;
#pragma unroll
                    for (int rr = 0; rr < 4; ++rr)
                        pk.h[rr] = __float2bfloat16(acc[at][ct][rr] * inv);
                    *(uint2*)(sGT + col * 144 + at * 32 + g4 * 8) = pk.u;
                }
            }
        } else {
            // direct pack, no normalization
#pragma unroll
            for (int ct = 0; ct < 4; ++ct) {
                int col = ct * 16 + l15;
#pragma unroll
                for (int at = 0; at < 4; ++at) {
                    union { __hip_bfloat16 h[4]; uint2 u; } pk;
#pragma unroll
                    for (int rr = 0; rr < 4; ++rr)
                        pk.h[rr] = __float2bfloat16(acc[at][ct][rr]);
                    *(uint2*)(sGT + col * 144 + at * 32 + g4 * 8) = pk.u;
                }
            }
        }
    }

    // ---- output: Gout[id*4096 + c*64 + a] = W[a][c]; lane -> col = lane ----
    {
        char* go = (char*)(Gout + (size_t)id * 4096 + lane * 64);
#pragma unroll
        for (int i = 0; i < 8; ++i)
            *(uint4*)(go + i * 16) = *(const uint4*)(sGT + lane * 144 + i * 16);
    }
    if (g4 == 0)
#pragma unroll
        for (int ct = 0; ct < 4; ++ct)
            Rout[(size_t)id * 64 + ct * 16 + l15] = rlog[ct];
}

// ---------------- combine: ONE WAVE per sequence, barrier-free ----------------
__global__ __launch_bounds__(64) void combine_kern(const __hip_bfloat16* __restrict__ G,
                                                   const float* __restrict__ R,
                                                   const float* __restrict__ sw,
                                                   const float* __restrict__ sb,
                                                   float* __restrict__ out) {
    int n = blockIdx.x;
    int lane = threadIdx.x;
    __shared__ __align__(16) float sV[64];

    float alpha;
    {
        float v = sw[lane] + sb[lane];
        float m = v;
#pragma unroll
        for (int off = 1; off < 64; off <<= 1) m = fmaxf(m, __shfl_xor(m, off, 64));
        float s = __expf(v - m);
#pragma unroll
        for (int off = 1; off < 64; off <<= 1) s += __shfl_xor(s, off, 64);
        alpha = v - (m + __logf(s));
    }

    const char* Gb = (const char*)(G + (size_t)n * CHUNKS * 4096) + lane * 128;
    const float* Rb = R + (size_t)n * CHUNKS * 64 + lane;

    uint4 pf[8];
#pragma unroll
    for (int i = 0; i < 8; ++i) pf[i] = *(const uint4*)(Gb + i * 16);
    float rpf = Rb[0];

    for (int c = 0; c < CHUNKS; ++c) {
        uint4 cur[8];
#pragma unroll
        for (int i = 0; i < 8; ++i) cur[i] = pf[i];
        float rc = rpf;
        if (c + 1 < CHUNKS) {
            const char* gn = Gb + (size_t)(c + 1) * 8192;
#pragma unroll
            for (int i = 0; i < 8; ++i) pf[i] = *(const uint4*)(gn + i * 16);
            rpf = Rb[(c + 1) * 64];
        }

        float m = alpha;
#pragma unroll
        for (int off = 1; off < 64; off <<= 1) m = fmaxf(m, __shfl_xor(m, off, 64));
        sV[lane] = __expf(alpha - m);
        float acc = 0.f;
        const float4* sv4 = (const float4*)sV;
#pragma unroll
        for (int i = 0; i < 8; ++i) {
            const uint32_t* gw = (const uint32_t*)&cur[i];
            float4 va = sv4[2 * i], vb = sv4[2 * i + 1];
            acc += va.x * bflo(gw[0]) + va.y * bfhi(gw[0]);
            acc += va.z * bflo(gw[1]) + va.w * bfhi(gw[1]);
            acc += vb.x * bflo(gw[2]) + vb.y * bfhi(gw[2]);
            acc += vb.z * bflo(gw[3]) + vb.w * bfhi(gw[3]);
        }
        alpha = m + __logf(fmaxf(acc, 1e-38f)) + rc;
    }

    {
        float m = alpha;
#pragma unroll
        for (int off = 1; off < 64; off <<= 1) m = fmaxf(m, __shfl_xor(m, off, 64));
        float s = __expf(alpha - m);
#pragma unroll
        for (int off = 1; off < 64; off <<= 1) s += __shfl_xor(s, off, 64);
        if (lane == 0) atomicAdd(out, -(m + __logf(s)) * (1.0f / 64.0f));
    }
}

extern "C" void kernel_launch(void* const* d_in, const int* in_sizes, int n_in,
                              void* d_out, int out_size, void* d_ws, size_t ws_size,
                              hipStream_t stream) {
    const int*   x   = (const int*)d_in[0];
    const float* emb = (const float*)d_in[1];
    const float* Wt  = (const float*)d_in[2];
    const float* sw  = (const float*)d_in[3];
    const float* sb  = (const float*)d_in[4];
    const float* ec  = (const float*)d_in[5];
    const float* vw  = (const float*)d_in[6];
    float* out = (float*)d_out;
    char* ws = (char*)d_ws;

    __hip_bfloat16* Eg  = (__hip_bfloat16*)ws;                         // 134,217,728 B
    __hip_bfloat16* A   = (__hip_bfloat16*)(ws + 134217728ull);        //   4,194,304 B
    __hip_bfloat16* B   = (__hip_bfloat16*)(ws + 138412032ull);        //   1,048,576 B
    __hip_bfloat16* emB = (__hip_bfloat16*)(ws + 139460608ull);        //   2,097,152 B
    float* partials     = (float*)(ws + 141557760ull);                 //     131,072 B
    __hip_bfloat16* Gc  = (__hip_bfloat16*)(ws + 141688832ull);        //   8,912,896 B
    float* Rc           = (float*)(ws + 150601728ull);                 //     278,528 B
                                                                       // end 150,880,256

    prep_dk<<<1536, 256, 0, stream>>>(x, emb, Wt, ec, vw, A, B, partials);
    emit_kern<<<510, 256, 0, stream>>>(x, ec, vw, partials, emB);
    gemm_kern<<<dim3(NTPAD / 128, NCOLS / 128), 256, 0, stream>>>(A, B, emB, Eg);
    chunk_kern<<<NSEQ * CHUNKS, 64, 0, stream>>>(Eg, Gc, Rc, out);
    combine_kern<<<NSEQ, 64, 0, stream>>>(Gc, Rc, sw, sb, out);
}